// Round 1
// baseline (120.533 us; speedup 1.0000x reference)
//
#include <hip/hip_runtime.h>
#include <stdint.h>

typedef float f32x4 __attribute__((ext_vector_type(4)));
typedef __bf16 bf16x8 __attribute__((ext_vector_type(8)));
typedef unsigned short u16;
typedef unsigned int u32;

#define N_NODES 8192
#define F_IN 512
#define F_OUT 128
#define LRA 0.2f

__device__ __forceinline__ u16 f32_to_bf16(float f) {
  union { float f; u32 u; } v; v.f = f;
  u32 u = v.u;
  u += 0x7fffu + ((u >> 16) & 1u);   // round-to-nearest-even
  return (u16)(u >> 16);
}
__device__ __forceinline__ float bf16_to_f32(u16 h) {
  union { u32 u; float f; } v; v.u = ((u32)h) << 16;
  return v.f;
}

// ---------------------------------------------------------------------------
// Kernel 1: Wh = h @ W (fp32), fused epilogue:
//   WhT (bf16, [F_OUT][N]) for the PV MFMA B-operand,
//   Wh1 = Wh @ a[:128], Wh2 = Wh @ a[128:]  (fp32)
// BM=32, BN=128(=full F_OUT), BK=32, 256 threads, micro-tile 4x4.
// ---------------------------------------------------------------------------
__global__ __launch_bounds__(256) void gemm_wh(
    const float* __restrict__ h, const float* __restrict__ W,
    const float* __restrict__ av,
    u16* __restrict__ WhT, float* __restrict__ Wh1, float* __restrict__ Wh2) {
  __shared__ float At[32][36];    // k-major A tile (transposed), padded
  __shared__ float Bs[32][132];   // [k][d] tile, padded; reused as output stash
  const int t = threadIdx.x;
  const int i0 = blockIdx.x * 32;
  const int tm = t >> 5, tn = t & 31;       // 8 x 32 thread grid, 4x4 micro
  const int lrow = t >> 3, lc = t & 7;      // staging map

  f32x4 acc[4];
#pragma unroll
  for (int r = 0; r < 4; ++r) acc[r] = (f32x4){0.f, 0.f, 0.f, 0.f};

  for (int kc = 0; kc < F_IN; kc += 32) {
    f32x4 a4 = *(const f32x4*)&h[(size_t)(i0 + lrow) * F_IN + kc + lc * 4];
    At[lc * 4 + 0][lrow] = a4[0];
    At[lc * 4 + 1][lrow] = a4[1];
    At[lc * 4 + 2][lrow] = a4[2];
    At[lc * 4 + 3][lrow] = a4[3];
#pragma unroll
    for (int q = 0; q < 4; ++q) {
      int c = (lc + q * 8) * 4;
      *(f32x4*)&Bs[lrow][c] = *(const f32x4*)&W[(size_t)(kc + lrow) * F_OUT + c];
    }
    __syncthreads();
#pragma unroll
    for (int k = 0; k < 32; ++k) {
      f32x4 b4 = *(f32x4*)&Bs[k][tn * 4];
      f32x4 a4k = *(f32x4*)&At[k][tm * 4];
#pragma unroll
      for (int r = 0; r < 4; ++r) acc[r] += b4 * a4k[r];
    }
    __syncthreads();
  }

  // stash full 32x128 tile into LDS for transpose + row dots
#pragma unroll
  for (int r = 0; r < 4; ++r) *(f32x4*)&Bs[tm * 4 + r][tn * 4] = acc[r];
  __syncthreads();

  // WhT bf16 write: [d][i] layout, coalesced 32B per thread
  {
    const int d = t >> 1, ih = (t & 1) * 16;
    u32 u[8];
#pragma unroll
    for (int e = 0; e < 8; ++e) {
      u32 lo = f32_to_bf16(Bs[ih + 2 * e][d]);
      u32 hi = f32_to_bf16(Bs[ih + 2 * e + 1][d]);
      u[e] = lo | (hi << 16);
    }
    u32* dst = (u32*)&WhT[(size_t)d * N_NODES + i0 + ih];
    uint4 v0; v0.x = u[0]; v0.y = u[1]; v0.z = u[2]; v0.w = u[3];
    uint4 v1; v1.x = u[4]; v1.y = u[5]; v1.z = u[6]; v1.w = u[7];
    *(uint4*)dst = v0;
    *(uint4*)(dst + 4) = v1;
  }

  // Wh1/Wh2: per-row dot with a[0:128] and a[128:256]
  {
    const int w = t >> 6, l = t & 63;
#pragma unroll
    for (int rr = 0; rr < 8; ++rr) {
      int row = w * 8 + rr;
      float x0 = Bs[row][l], x1 = Bs[row][l + 64];
      float s1 = x0 * av[l] + x1 * av[l + 64];
      float s2 = x0 * av[128 + l] + x1 * av[192 + l];
#pragma unroll
      for (int m = 32; m >= 1; m >>= 1) {
        s1 += __shfl_xor(s1, m, 64);
        s2 += __shfl_xor(s2, m, 64);
      }
      if (l == 0) { Wh1[i0 + row] = s1; Wh2[i0 + row] = s2; }
    }
  }
}

// ---------------------------------------------------------------------------
// Kernel 2: flash-style masked-softmax attention, bf16 MFMA PV.
// Tile: 64 rows (i) x 64 cols (j) per chunk. 4 waves; wave w owns d in
// [w*32, w*32+32). P rounded to bf16; denominator summed from the SAME
// rounded values (exact convex combination). No max subtraction needed:
// e = lrelu(Wh1[i]+Wh2[j]) is in [-1.5, +6] -> exp never over/underflows.
// j-split across `js` block groups; partials (num, denom) to workspace.
// ---------------------------------------------------------------------------
__global__ __launch_bounds__(256) void gat_main(
    const int* __restrict__ adj, const float* __restrict__ Wh1,
    const float* __restrict__ Wh2, const u16* __restrict__ WhT,
    float* __restrict__ accp, float* __restrict__ sp,
    const int js, const int jlen) {
  __shared__ u16 Plds[64][72];    // P tile, bf16, +8 pad (bank spread)
  __shared__ u16 Vlds[128][72];   // V^T tile: [d][j], bf16, +8 pad
  __shared__ float sscr[256];

  const int t = threadIdx.x;
  const int bi = (int)blockIdx.x / js;
  const int jsi = (int)blockIdx.x % js;
  const int i0 = bi * 64;
  const int j0 = jsi * jlen;

  const int vd = t >> 1, vh = (t & 1) * 32;     // V staging map
  const int il = t >> 2, q4 = (t & 3) * 16;     // P staging map
  const float cI = Wh1[i0 + il];
  const int w = t >> 6, l = t & 63, r = l & 15, oct = l >> 4;

  f32x4 acc[4][2];
#pragma unroll
  for (int it = 0; it < 4; ++it)
#pragma unroll
    for (int dt = 0; dt < 2; ++dt) acc[it][dt] = (f32x4){0.f, 0.f, 0.f, 0.f};
  float sAcc = 0.f;

  for (int ch = 0; ch < jlen; ch += 64) {
    const int jc = j0 + ch;

    // ---- stage V^T tile (L2-resident WhT) ----
#pragma unroll
    for (int q = 0; q < 4; ++q) {
      uint4 v = *(const uint4*)&WhT[(size_t)vd * N_NODES + jc + vh + q * 8];
      *(uint4*)&Vlds[vd][vh + q * 8] = v;
    }

    // ---- stage P tile: adj (coalesced, the HBM-critical read) -> p bf16 ----
    const int* arow = &adj[(size_t)(i0 + il) * N_NODES + jc + q4];
    const float* w2p = &Wh2[jc + q4];
#pragma unroll
    for (int k = 0; k < 4; ++k) {
      int4 a4 = *(const int4*)&arow[k * 4];
      f32x4 w2 = *(const f32x4*)&w2p[k * 4];
      int ai[4] = {a4.x, a4.y, a4.z, a4.w};
      u16 pu[4];
#pragma unroll
      for (int e = 0; e < 4; ++e) {
        float x = cI + w2[e];
        x = x >= 0.f ? x : LRA * x;       // LeakyReLU
        float p = __expf(x);
        p = ai[e] ? p : 0.f;              // adjacency mask
        u16 b = f32_to_bf16(p);
        pu[e] = b;
        sAcc += bf16_to_f32(b);           // denom from rounded values
      }
      ushort4 pv; pv.x = pu[0]; pv.y = pu[1]; pv.z = pu[2]; pv.w = pu[3];
      *(ushort4*)&Plds[il][q4 + k * 4] = pv;
    }
    __syncthreads();

    // ---- MFMA: acc[i-tile][d-tile] += P[16x32] x V[32x16] ----
#pragma unroll
    for (int ks = 0; ks < 2; ++ks) {
      const int col = ks * 32 + oct * 8;
      bf16x8 b0 = *(bf16x8*)&Vlds[w * 32 + r][col];
      bf16x8 b1 = *(bf16x8*)&Vlds[w * 32 + 16 + r][col];
#pragma unroll
      for (int it = 0; it < 4; ++it) {
        bf16x8 af = *(bf16x8*)&Plds[it * 16 + r][col];
        acc[it][0] = __builtin_amdgcn_mfma_f32_16x16x32_bf16(af, b0, acc[it][0], 0, 0, 0);
        acc[it][1] = __builtin_amdgcn_mfma_f32_16x16x32_bf16(af, b1, acc[it][1], 0, 0, 0);
      }
    }
    __syncthreads();
  }

  // ---- epilogue: denominator partials ----
  sscr[t] = sAcc;
  __syncthreads();
  if (t < 64) {
    float s = sscr[4 * t] + sscr[4 * t + 1] + sscr[4 * t + 2] + sscr[4 * t + 3];
    sp[(size_t)jsi * N_NODES + i0 + t] = s;
  }

  // ---- numerator partials: C layout col=lane&15, row=(lane>>4)*4+reg ----
#pragma unroll
  for (int it = 0; it < 4; ++it) {
#pragma unroll
    for (int dt = 0; dt < 2; ++dt) {
#pragma unroll
      for (int rr = 0; rr < 4; ++rr) {
        int row = i0 + it * 16 + oct * 4 + rr;
        int dcol = w * 32 + dt * 16 + r;
        accp[((size_t)jsi * N_NODES + row) * F_OUT + dcol] = acc[it][dt][rr];
      }
    }
  }
}

// ---------------------------------------------------------------------------
// Kernel 3: reduce j-split partials, divide, ELU.
// ---------------------------------------------------------------------------
__global__ __launch_bounds__(256) void finalize_k(
    const float* __restrict__ accp, const float* __restrict__ sp,
    float* __restrict__ out, const int js) {
  const int idx = blockIdx.x * 256 + threadIdx.x;
  const int i = idx >> 7;
  float num = 0.f, den = 0.f;
  for (int s = 0; s < js; ++s) {
    num += accp[(size_t)s * (N_NODES * F_OUT) + idx];
    den += sp[(size_t)s * N_NODES + i];
  }
  float x = num / den;
  out[idx] = x > 0.f ? x : expm1f(x);
}

// ---------------------------------------------------------------------------
extern "C" void kernel_launch(void* const* d_in, const int* in_sizes, int n_in,
                              void* d_out, int out_size, void* d_ws, size_t ws_size,
                              hipStream_t stream) {
  const float* h = (const float*)d_in[0];
  const int* adj = (const int*)d_in[1];
  const float* W = (const float*)d_in[2];
  const float* av = (const float*)d_in[3];
  float* out = (float*)d_out;
  char* ws = (char*)d_ws;

  // workspace layout
  u16* WhT = (u16*)ws;                                     // 2 MB
  float* Wh1 = (float*)(ws + (2ull << 20));                // 32 KB
  float* Wh2 = (float*)(ws + (2ull << 20) + (32ull << 10));// 32 KB
  float* sp = (float*)(ws + (2ull << 20) + (64ull << 10)); // <= 256 KB
  float* accp = (float*)(ws + (2ull << 20) + (320ull << 10));
  const size_t base = (2ull << 20) + (320ull << 10);

  int js = 8;
  while (js > 1 && base + (size_t)js * N_NODES * F_OUT * 4 > ws_size) js >>= 1;
  const int jlen = N_NODES / js;

  gemm_wh<<<N_NODES / 32, 256, 0, stream>>>(h, W, av, WhT, Wh1, Wh2);
  gat_main<<<(N_NODES / 64) * js, 256, 0, stream>>>(adj, Wh1, Wh2, WhT, accp, sp, js, jlen);
  finalize_k<<<(N_NODES * F_OUT) / 256, 256, 0, stream>>>(accp, sp, out, js);
}

// Round 2
// 113.309 us; speedup vs baseline: 1.0638x; 1.0638x over previous
//
#include <hip/hip_runtime.h>
#include <stdint.h>

typedef float f32x4 __attribute__((ext_vector_type(4)));
typedef __bf16 bf16x8 __attribute__((ext_vector_type(8)));
typedef unsigned short u16;
typedef unsigned int u32;

#define N_NODES 8192
#define F_IN 512
#define F_OUT 128
#define LRA 0.2f

__device__ __forceinline__ u16 f32_to_bf16(float f) {
  union { float f; u32 u; } v; v.f = f;
  u32 u = v.u;
  u += 0x7fffu + ((u >> 16) & 1u);   // round-to-nearest-even
  return (u16)(u >> 16);
}
__device__ __forceinline__ float bf16_to_f32(u16 h) {
  union { u32 u; float f; } v; v.u = ((u32)h) << 16;
  return v.f;
}
__device__ __forceinline__ float dot4(f32x4 a, f32x4 b) {
  return a[0] * b[0] + a[1] * b[1] + a[2] * b[2] + a[3] * b[3];
}

// ---------------------------------------------------------------------------
// prep_k: WT[d][k] = bf16(W[k][d])  (128 x 512), and wa = [W@a1 ; W@a2] fp32.
// 16 blocks, each handles a 32-k chunk. LDS transpose for coalesced I/O.
// ---------------------------------------------------------------------------
__global__ __launch_bounds__(256) void prep_k(
    const float* __restrict__ W, const float* __restrict__ av,
    u16* __restrict__ WT, float* __restrict__ wa) {
  __shared__ u16 Ts[F_OUT][40];
  const int t = threadIdx.x, kc = (int)blockIdx.x * 32;
  {
    const int k = t >> 3, dof = (t & 7) * 16;
#pragma unroll
    for (int q = 0; q < 4; ++q) {
      f32x4 v = *(const f32x4*)&W[(size_t)(kc + k) * F_OUT + dof + q * 4];
#pragma unroll
      for (int e = 0; e < 4; ++e) Ts[dof + q * 4 + e][k] = f32_to_bf16(v[e]);
    }
  }
  __syncthreads();
  {
    const int d = t >> 1, kh = (t & 1) * 16;
    uint4 o0 = *(uint4*)&Ts[d][kh];
    uint4 o1 = *(uint4*)&Ts[d][kh + 8];
    *(uint4*)&WT[(size_t)d * F_IN + kc + kh] = o0;
    *(uint4*)&WT[(size_t)d * F_IN + kc + kh + 8] = o1;
  }
  {
    const int kl = t >> 3, l8 = t & 7;
    const float* wrow = &W[(size_t)(kc + kl) * F_OUT];
    float s1 = 0.f, s2 = 0.f;
#pragma unroll
    for (int q = 0; q < 2; ++q) {
      int dd = l8 * 16 + q * 8;
      f32x4 w0 = *(const f32x4*)&wrow[dd];
      f32x4 w1 = *(const f32x4*)&wrow[dd + 4];
      s1 += dot4(w0, *(const f32x4*)&av[dd]) + dot4(w1, *(const f32x4*)&av[dd + 4]);
      s2 += dot4(w0, *(const f32x4*)&av[F_OUT + dd]) + dot4(w1, *(const f32x4*)&av[F_OUT + dd + 4]);
    }
#pragma unroll
    for (int m = 1; m <= 4; m <<= 1) {
      s1 += __shfl_xor(s1, m, 64);
      s2 += __shfl_xor(s2, m, 64);
    }
    if (l8 == 0) { wa[kc + kl] = s1; wa[F_IN + kc + kl] = s2; }
  }
}

// ---------------------------------------------------------------------------
// gemm_wh: WhT[d][i] = bf16( (h @ W)[i][d] ) via 16x16x32 bf16 MFMA.
// Wh1/Wh2 computed EXACTLY in fp32 as h @ (W@a) fused into A-staging.
// BM=32, BN=128, BK=64. 256 blocks x 256 thr (4 waves: 2M x 2N).
// Double-buffered LDS, register prefetch, one barrier per K-iter.
// ---------------------------------------------------------------------------
__global__ __launch_bounds__(256) void gemm_wh(
    const float* __restrict__ h, const u16* __restrict__ WT,
    const float* __restrict__ wa,
    u16* __restrict__ WhT, float* __restrict__ Wh1, float* __restrict__ Wh2) {
  __shared__ u16 Ab[2][32][80];
  __shared__ u16 Bs[2][F_OUT][80];
  const int t = threadIdx.x;
  const int i0 = (int)blockIdx.x * 32;
  const int w = t >> 6, l = t & 63, r = l & 15, oct = l >> 4;
  const int mrow = (w & 1) * 16, ncol = (w >> 1) * 64;
  const int ar = t >> 3, ak = (t & 7) * 8;   // A staging: row, k-slice
  const int br = t >> 1, bk = (t & 1) * 32;  // B staging: d-row, k-slice

  const float* hrow = &h[(size_t)(i0 + ar) * F_IN + ak];
  const u16* wtrow = &WT[(size_t)br * F_IN + bk];
  const float* wap = &wa[ak];
  const float* wbp = &wa[F_IN + ak];

  f32x4 acc[4];
#pragma unroll
  for (int nf = 0; nf < 4; ++nf) acc[nf] = (f32x4){0.f, 0.f, 0.f, 0.f};
  float s1 = 0.f, s2 = 0.f;

  f32x4 ra0, ra1;
  uint4 rb[4];

#define STORE_A(B)                                                        \
  { u32 p0 = f32_to_bf16(ra0[0]) | ((u32)f32_to_bf16(ra0[1]) << 16);      \
    u32 p1 = f32_to_bf16(ra0[2]) | ((u32)f32_to_bf16(ra0[3]) << 16);      \
    u32 p2 = f32_to_bf16(ra1[0]) | ((u32)f32_to_bf16(ra1[1]) << 16);      \
    u32 p3 = f32_to_bf16(ra1[2]) | ((u32)f32_to_bf16(ra1[3]) << 16);      \
    uint4 v; v.x = p0; v.y = p1; v.z = p2; v.w = p3;                      \
    *(uint4*)&Ab[B][ar][ak] = v; }
#define STORE_B(B)                                                        \
  { *(uint4*)&Bs[B][br][bk + 0]  = rb[0];                                 \
    *(uint4*)&Bs[B][br][bk + 8]  = rb[1];                                 \
    *(uint4*)&Bs[B][br][bk + 16] = rb[2];                                 \
    *(uint4*)&Bs[B][br][bk + 24] = rb[3]; }

  // prologue: it = 0
  ra0 = *(const f32x4*)&hrow[0];
  ra1 = *(const f32x4*)&hrow[4];
#pragma unroll
  for (int j = 0; j < 4; ++j) rb[j] = *(const uint4*)&wtrow[j * 8];
  s1 += dot4(ra0, *(const f32x4*)&wap[0]) + dot4(ra1, *(const f32x4*)&wap[4]);
  s2 += dot4(ra0, *(const f32x4*)&wbp[0]) + dot4(ra1, *(const f32x4*)&wbp[4]);
  STORE_A(0); STORE_B(0);
  __syncthreads();

#pragma unroll
  for (int it = 0; it < 8; ++it) {
    const int buf = it & 1;
    if (it < 7) {
      const int kc = (it + 1) * 64;
      ra0 = *(const f32x4*)&hrow[kc];
      ra1 = *(const f32x4*)&hrow[kc + 4];
#pragma unroll
      for (int j = 0; j < 4; ++j) rb[j] = *(const uint4*)&wtrow[kc + j * 8];
      s1 += dot4(ra0, *(const f32x4*)&wap[kc]) + dot4(ra1, *(const f32x4*)&wap[kc + 4]);
      s2 += dot4(ra0, *(const f32x4*)&wbp[kc]) + dot4(ra1, *(const f32x4*)&wbp[kc + 4]);
    }
#pragma unroll
    for (int ks = 0; ks < 2; ++ks) {
      bf16x8 af = *(bf16x8*)&Ab[buf][mrow + r][ks * 32 + oct * 8];
#pragma unroll
      for (int nf = 0; nf < 4; ++nf) {
        bf16x8 bfv = *(bf16x8*)&Bs[buf][ncol + nf * 16 + r][ks * 32 + oct * 8];
        acc[nf] = __builtin_amdgcn_mfma_f32_16x16x32_bf16(af, bfv, acc[nf], 0, 0, 0);
      }
    }
    if (it < 7) {
      STORE_A(buf ^ 1); STORE_B(buf ^ 1);
      __syncthreads();
    }
  }
#undef STORE_A
#undef STORE_B

  // Wh1/Wh2: reduce over the 8 k-slice lanes of each row
#pragma unroll
  for (int m = 1; m <= 4; m <<= 1) {
    s1 += __shfl_xor(s1, m, 64);
    s2 += __shfl_xor(s2, m, 64);
  }
  if ((t & 7) == 0) { Wh1[i0 + ar] = s1; Wh2[i0 + ar] = s2; }

  // WhT: C frag col=lane&15 (d), rows oct*4+rr (i) -> 4 consecutive i
#pragma unroll
  for (int nf = 0; nf < 4; ++nf) {
    u32 lo = f32_to_bf16(acc[nf][0]) | ((u32)f32_to_bf16(acc[nf][1]) << 16);
    u32 hi = f32_to_bf16(acc[nf][2]) | ((u32)f32_to_bf16(acc[nf][3]) << 16);
    const int d = ncol + nf * 16 + r;
    uint2 v; v.x = lo; v.y = hi;
    *(uint2*)&WhT[(size_t)d * N_NODES + i0 + mrow + oct * 4] = v;
  }
}

// ---------------------------------------------------------------------------
// gat_main: flash-style masked softmax attention. 64x64 tiles.
// V frags read DIRECTLY from L2-resident WhT (no LDS staging), issued before
// the exp/mask phase so latency hides under VALU. Plds double-buffered ->
// ONE barrier per chunk. Unshifted exp is safe: e in [-2, +7].
// ---------------------------------------------------------------------------
__global__ __launch_bounds__(256) void gat_main(
    const int* __restrict__ adj, const float* __restrict__ Wh1,
    const float* __restrict__ Wh2, const u16* __restrict__ WhT,
    float* __restrict__ accp, float* __restrict__ sp,
    const int js, const int jlen) {
  __shared__ u16 Plds[2][64][80];
  __shared__ float sscr[256];

  const int t = threadIdx.x;
  const int bi = (int)blockIdx.x / js;
  const int jsi = (int)blockIdx.x % js;
  const int i0 = bi * 64;
  const int j0 = jsi * jlen;

  const int il = t >> 2, q4 = (t & 3) * 16;     // P staging map
  const float cI = Wh1[i0 + il];
  const int w = t >> 6, l = t & 63, r = l & 15, oct = l >> 4;

  const u16* vp0 = &WhT[(size_t)(w * 32 + r) * N_NODES];
  const u16* vp1 = &WhT[(size_t)(w * 32 + 16 + r) * N_NODES];

  f32x4 acc[4][2];
#pragma unroll
  for (int it = 0; it < 4; ++it)
#pragma unroll
    for (int dt = 0; dt < 2; ++dt) acc[it][dt] = (f32x4){0.f, 0.f, 0.f, 0.f};
  float sAcc = 0.f;

  for (int ch = 0; ch < jlen; ch += 64) {
    const int jc = j0 + ch;
    const int buf = (ch >> 6) & 1;

    // ---- issue V fragment loads early (L2/L3) ----
    bf16x8 b00 = *(const bf16x8*)&vp0[jc + oct * 8];
    bf16x8 b01 = *(const bf16x8*)&vp0[jc + 32 + oct * 8];
    bf16x8 b10 = *(const bf16x8*)&vp1[jc + oct * 8];
    bf16x8 b11 = *(const bf16x8*)&vp1[jc + 32 + oct * 8];

    // ---- stage P tile: adj (the HBM-critical read) -> exp -> bf16 ----
    const int* arow = &adj[(size_t)(i0 + il) * N_NODES + jc + q4];
    const float* w2p = &Wh2[jc + q4];
#pragma unroll
    for (int k = 0; k < 4; ++k) {
      int4 a4 = *(const int4*)&arow[k * 4];
      f32x4 w2 = *(const f32x4*)&w2p[k * 4];
      int ai[4] = {a4.x, a4.y, a4.z, a4.w};
      u16 pu[4];
#pragma unroll
      for (int e = 0; e < 4; ++e) {
        float x = cI + w2[e];
        x = x >= 0.f ? x : LRA * x;       // LeakyReLU
        float p = __expf(x);
        p = ai[e] ? p : 0.f;              // adjacency mask
        u16 b = f32_to_bf16(p);
        pu[e] = b;
        sAcc += bf16_to_f32(b);           // denom from the SAME rounded values
      }
      ushort4 pv; pv.x = pu[0]; pv.y = pu[1]; pv.z = pu[2]; pv.w = pu[3];
      *(ushort4*)&Plds[buf][il][q4 + k * 4] = pv;
    }
    __syncthreads();   // single barrier per chunk (double-buffered Plds)

    // ---- MFMA: acc[i-tile][d-tile] += P[16x32] x V[32x16] ----
#pragma unroll
    for (int ks = 0; ks < 2; ++ks) {
      bf16x8 bA = ks ? b01 : b00;
      bf16x8 bB = ks ? b11 : b10;
#pragma unroll
      for (int it = 0; it < 4; ++it) {
        bf16x8 af = *(bf16x8*)&Plds[buf][it * 16 + r][ks * 32 + oct * 8];
        acc[it][0] = __builtin_amdgcn_mfma_f32_16x16x32_bf16(af, bA, acc[it][0], 0, 0, 0);
        acc[it][1] = __builtin_amdgcn_mfma_f32_16x16x32_bf16(af, bB, acc[it][1], 0, 0, 0);
      }
    }
  }

  // ---- denominator partials ----
  sscr[t] = sAcc;
  __syncthreads();
  if (t < 64) {
    float s = sscr[4 * t] + sscr[4 * t + 1] + sscr[4 * t + 2] + sscr[4 * t + 3];
    sp[(size_t)jsi * N_NODES + i0 + t] = s;
  }

  // ---- numerator partials: C layout col=lane&15, row=(lane>>4)*4+reg ----
#pragma unroll
  for (int it = 0; it < 4; ++it) {
#pragma unroll
    for (int dt = 0; dt < 2; ++dt) {
#pragma unroll
      for (int rr = 0; rr < 4; ++rr) {
        int row = i0 + it * 16 + oct * 4 + rr;
        int dcol = w * 32 + dt * 16 + r;
        accp[((size_t)jsi * N_NODES + row) * F_OUT + dcol] = acc[it][dt][rr];
      }
    }
  }
}

// ---------------------------------------------------------------------------
// finalize: reduce j-split partials, divide, ELU.
// ---------------------------------------------------------------------------
__global__ __launch_bounds__(256) void finalize_k(
    const float* __restrict__ accp, const float* __restrict__ sp,
    float* __restrict__ out, const int js) {
  const int idx = (int)blockIdx.x * 256 + threadIdx.x;
  const int i = idx >> 7;
  float num = 0.f, den = 0.f;
  for (int s = 0; s < js; ++s) {
    num += accp[(size_t)s * (N_NODES * F_OUT) + idx];
    den += sp[(size_t)s * N_NODES + i];
  }
  float x = num / den;
  out[idx] = x > 0.f ? x : expm1f(x);
}

// ---------------------------------------------------------------------------
extern "C" void kernel_launch(void* const* d_in, const int* in_sizes, int n_in,
                              void* d_out, int out_size, void* d_ws, size_t ws_size,
                              hipStream_t stream) {
  const float* h = (const float*)d_in[0];
  const int* adj = (const int*)d_in[1];
  const float* W = (const float*)d_in[2];
  const float* av = (const float*)d_in[3];
  float* out = (float*)d_out;
  char* ws = (char*)d_ws;

  // workspace layout
  u16* WT = (u16*)ws;                                   // 128 KB
  float* wa = (float*)(ws + (256ull << 10));            // 4 KB
  u16* WhT = (u16*)(ws + (512ull << 10));               // 2 MB
  float* Wh1 = (float*)(ws + (512ull << 10) + (2ull << 20));
  float* Wh2 = (float*)(ws + (512ull << 10) + (2ull << 20) + (32ull << 10));
  float* sp = (float*)(ws + (512ull << 10) + (2ull << 20) + (64ull << 10));
  float* accp = (float*)(ws + (512ull << 10) + (2ull << 20) + (320ull << 10));
  const size_t base = (512ull << 10) + (2ull << 20) + (320ull << 10);

  int js = 8;
  while (js > 1 && base + (size_t)js * N_NODES * F_OUT * 4 > ws_size) js >>= 1;
  const int jlen = N_NODES / js;

  prep_k<<<16, 256, 0, stream>>>(W, av, WT, wa);
  gemm_wh<<<N_NODES / 32, 256, 0, stream>>>(h, WT, wa, WhT, Wh1, Wh2);
  gat_main<<<(N_NODES / 64) * js, 256, 0, stream>>>(adj, Wh1, Wh2, WhT, accp, sp, js, jlen);
  finalize_k<<<(N_NODES * F_OUT) / 256, 256, 0, stream>>>(accp, sp, out, js);
}